// Round 1
// baseline (3857.998 us; speedup 1.0000x reference)
//
#include <hip/hip_runtime.h>

#define N_NODES 32768
#define M_EDGES 8192
#define IN_DIM  256
#define OUT_F   64

// ---------------------------------------------------------------------------
// Kernel 1: Dv_raw[n] = sum_m H[n,m] * w[m]   (weighted row sums)
// Block owns 64 rows, scans all M columns. One wave per row; no atomics.
// ---------------------------------------------------------------------------
__global__ __launch_bounds__(256) void k_dv(const float* __restrict__ H,
                                            const float* __restrict__ w,
                                            float* __restrict__ Dv_raw) {
    __shared__ float w_s[M_EDGES];   // 32 KB
    int tid = threadIdx.x;
    for (int i = tid; i < M_EDGES; i += 256) w_s[i] = w[i];
    __syncthreads();
    int lane = tid & 63;
    int wid  = tid >> 6;             // 0..3
    int row0 = blockIdx.x * 64;
    for (int r = wid; r < 64; r += 4) {
        int row = row0 + r;
        const float* Hrow = H + (size_t)row * M_EDGES;
        float a0 = 0.f, a1 = 0.f, a2 = 0.f, a3 = 0.f;
        for (int c = lane; c < M_EDGES; c += 256) {
            a0 = fmaf(Hrow[c],       w_s[c],       a0);
            a1 = fmaf(Hrow[c + 64],  w_s[c + 64],  a1);
            a2 = fmaf(Hrow[c + 128], w_s[c + 128], a2);
            a3 = fmaf(Hrow[c + 192], w_s[c + 192], a3);
        }
        float a = (a0 + a1) + (a2 + a3);
        for (int off = 32; off; off >>= 1) a += __shfl_down(a, off, 64);
        if (lane == 0) Dv_raw[row] = a;
    }
}

// ---------------------------------------------------------------------------
// Kernel 2: z[n,k] = rsqrt(max(Dv[n],1e-6)) * (x[n,:] @ W[:,k] + b[k])
// Block: 4 rows x 64 cols. x rows staged in LDS; W rows L2-resident.
// ---------------------------------------------------------------------------
__global__ __launch_bounds__(256) void k_lin(const float* __restrict__ x,
                                             const float* __restrict__ Wl,
                                             const float* __restrict__ b,
                                             const float* __restrict__ Dv_raw,
                                             float* __restrict__ z) {
    __shared__ float x_s[4 * IN_DIM];
    int tid = threadIdx.x;
    int n0 = blockIdx.x * 4;
    for (int i = 0; i < 4; ++i)
        x_s[i * IN_DIM + tid] = x[(size_t)(n0 + i) * IN_DIM + tid];
    __syncthreads();
    int r = tid >> 6;
    int k = tid & 63;
    float acc = b[k];
    const float* xr = x_s + r * IN_DIM;
    #pragma unroll 8
    for (int i = 0; i < IN_DIM; ++i)
        acc = fmaf(xr[i], Wl[i * OUT_F + k], acc);
    float dvis = rsqrtf(fmaxf(Dv_raw[n0 + r], 1e-6f));
    z[(size_t)(n0 + r) * OUT_F + k] = dvis * acc;
}

// ---------------------------------------------------------------------------
// Kernel 3: t[m,:] = sum_n H[n,m] * z[n,:]  and  De_raw[m] = sum_n H[n,m]
// Scan-compact-process: block owns a 32-column stripe, scans a row chunk,
// ballot-compacts nonzeros into an LDS queue, then one wave per nonzero
// scatters z[n,:] into the LDS t-tile (lane = feature).
// ---------------------------------------------------------------------------
#define C3  32
#define T3  512
#define QS3 2048
#define W3  64    // scan iterations per drain window

__global__ __launch_bounds__(512) void k_edge(const float* __restrict__ H,
                                              const float* __restrict__ z,
                                              float* __restrict__ t,
                                              float* __restrict__ De_raw) {
    __shared__ float t_s[C3 * OUT_F];      // 8 KB
    __shared__ unsigned int q[QS3];        // 8 KB
    __shared__ float de_s[C3];
    __shared__ unsigned int qcount;
    int tid = threadIdx.x;
    int m0 = blockIdx.x * C3;
    int rows_per_chunk = N_NODES / gridDim.y;
    int row_base0 = blockIdx.y * rows_per_chunk;

    for (int i = tid; i < C3 * OUT_F; i += T3) t_s[i] = 0.f;
    if (tid < C3) de_s[tid] = 0.f;
    if (tid == 0) qcount = 0;
    __syncthreads();

    int lane = tid & 63;
    int wid  = tid >> 6;
    int c  = tid & (C3 - 1);   // 0..31  (column within stripe)
    int rl = tid >> 5;         // 0..15  (row within iteration)
    float de_acc = 0.f;

    const int ROWS_PER_IT = T3 / C3;                    // 16
    const int iters = rows_per_chunk / ROWS_PER_IT;     // e.g. 1024

    const float* Hc = H + (size_t)m0 + (size_t)c;

    for (int itb = 0; itb < iters; itb += W3) {
        // ---- scan window (unrolled x4 so loads can be batched) ----
        for (int it = itb; it < itb + W3; it += 4) {
            int row = row_base0 + it * ROWS_PER_IT + rl;
            float h0 = Hc[(size_t)(row)                   * M_EDGES];
            float h1 = Hc[(size_t)(row + ROWS_PER_IT)     * M_EDGES];
            float h2 = Hc[(size_t)(row + 2 * ROWS_PER_IT) * M_EDGES];
            float h3 = Hc[(size_t)(row + 3 * ROWS_PER_IT) * M_EDGES];
            #define APPEND3(hv, rowv)                                          \
            {                                                                  \
                de_acc += (hv);                                                \
                bool nz = ((hv) != 0.f);                                       \
                unsigned long long mask = __ballot(nz);                        \
                unsigned int cnt = (unsigned int)__popcll(mask);               \
                unsigned int base = 0;                                         \
                if (lane == 0 && cnt) base = atomicAdd(&qcount, cnt);          \
                base = __shfl(base, 0, 64);                                    \
                if (nz) {                                                      \
                    unsigned int off = base +                                  \
                        (unsigned int)__popcll(mask & ((1ull << lane) - 1));   \
                    q[off] = ((unsigned int)(rowv) << 5) | (unsigned int)c;    \
                }                                                              \
            }
            APPEND3(h0, row)
            APPEND3(h1, row + ROWS_PER_IT)
            APPEND3(h2, row + 2 * ROWS_PER_IT)
            APPEND3(h3, row + 3 * ROWS_PER_IT)
            #undef APPEND3
        }
        // ---- drain: one wave per queue entry, lane = feature ----
        __syncthreads();
        unsigned int nq = qcount;
        for (unsigned int i = wid; i < nq; i += (T3 / 64)) {
            unsigned int e = q[i];
            int row = e >> 5;
            int cl  = e & (C3 - 1);
            float v = z[(size_t)row * OUT_F + lane];
            atomicAdd(&t_s[cl * OUT_F + lane], v);
        }
        __syncthreads();
        if (tid == 0) qcount = 0;
        __syncthreads();
    }

    atomicAdd(&de_s[c], de_acc);
    __syncthreads();
    // merge partial results (gridDim.y row chunks share a stripe)
    for (int i = tid; i < C3 * OUT_F; i += T3)
        atomicAdd(&t[(size_t)m0 * OUT_F + i], t_s[i]);
    if (tid < C3) atomicAdd(&De_raw[m0 + tid], de_s[tid]);
}

// ---------------------------------------------------------------------------
// Kernel 4: t[m,k] *= w[m] / max(De[m], 1)
// ---------------------------------------------------------------------------
__global__ __launch_bounds__(256) void k_scale(float* __restrict__ t,
                                               const float* __restrict__ w,
                                               const float* __restrict__ De_raw) {
    int idx = blockIdx.x * 256 + threadIdx.x;
    int m = idx >> 6;
    float s = w[m] / fmaxf(De_raw[m], 1.0f);
    t[idx] *= s;
}

// ---------------------------------------------------------------------------
// Kernel 5: out[n,:] = dvis[n] * sum_m H[n,m] * t[m,:]
// Block owns 64 rows, scans all M columns. No atomics on global out.
// ---------------------------------------------------------------------------
#define R5  64
#define T5  512
#define QS5 2048
#define W5  64

__global__ __launch_bounds__(512) void k_node(const float* __restrict__ H,
                                              const float* __restrict__ t,
                                              const float* __restrict__ Dv_raw,
                                              float* __restrict__ out) {
    __shared__ float o_s[R5 * OUT_F];     // 16 KB
    __shared__ unsigned int q[QS5];       // 8 KB
    __shared__ unsigned int qcount;
    int tid = threadIdx.x;
    int n0 = blockIdx.x * R5;
    for (int i = tid; i < R5 * OUT_F; i += T5) o_s[i] = 0.f;
    if (tid == 0) qcount = 0;
    __syncthreads();
    int lane = tid & 63;
    int wid  = tid >> 6;

    const int CPR = M_EDGES / T5;       // col-chunks per row = 16
    const int iters = R5 * CPR;         // 1024

    for (int itb = 0; itb < iters; itb += W5) {
        for (int it = itb; it < itb + W5; it += 4) {
            #define APPEND5(ii)                                                \
            {                                                                  \
                int r  = (ii) >> 4;                                            \
                int m  = ((ii) & (CPR - 1)) * T5 + tid;                        \
                float h = H[(size_t)(n0 + r) * M_EDGES + m];                   \
                bool nz = (h != 0.f);                                          \
                unsigned long long mask = __ballot(nz);                        \
                unsigned int cnt = (unsigned int)__popcll(mask);               \
                unsigned int base = 0;                                         \
                if (lane == 0 && cnt) base = atomicAdd(&qcount, cnt);          \
                base = __shfl(base, 0, 64);                                    \
                if (nz) {                                                      \
                    unsigned int off = base +                                  \
                        (unsigned int)__popcll(mask & ((1ull << lane) - 1));   \
                    q[off] = ((unsigned int)r << 13) | (unsigned int)m;        \
                }                                                              \
            }
            APPEND5(it)
            APPEND5(it + 1)
            APPEND5(it + 2)
            APPEND5(it + 3)
            #undef APPEND5
        }
        __syncthreads();
        unsigned int nq = qcount;
        for (unsigned int i = wid; i < nq; i += (T5 / 64)) {
            unsigned int e = q[i];
            int r = e >> 13;
            int m = e & (M_EDGES - 1);
            float v = t[(size_t)m * OUT_F + lane];
            atomicAdd(&o_s[r * OUT_F + lane], v);
        }
        __syncthreads();
        if (tid == 0) qcount = 0;
        __syncthreads();
    }
    for (int i = tid; i < R5 * OUT_F; i += T5) {
        int r = i >> 6;
        float dvis = rsqrtf(fmaxf(Dv_raw[n0 + r], 1e-6f));
        out[(size_t)n0 * OUT_F + i] = dvis * o_s[i];
    }
}

// ---------------------------------------------------------------------------
extern "C" void kernel_launch(void* const* d_in, const int* in_sizes, int n_in,
                              void* d_out, int out_size, void* d_ws, size_t ws_size,
                              hipStream_t stream) {
    const float* x  = (const float*)d_in[0];
    const float* H  = (const float*)d_in[1];
    const float* w  = (const float*)d_in[2];
    const float* Wl = (const float*)d_in[3];
    const float* bl = (const float*)d_in[4];
    float* out = (float*)d_out;

    // workspace layout (floats): z[N*64] | t[M*64] | Dv[N] | De[M]  (~10.7 MB)
    float* z      = (float*)d_ws;
    float* t      = z + (size_t)N_NODES * OUT_F;
    float* Dv_raw = t + (size_t)M_EDGES * OUT_F;
    float* De_raw = Dv_raw + N_NODES;

    hipMemsetAsync(t, 0, (size_t)M_EDGES * OUT_F * sizeof(float), stream);
    hipMemsetAsync(De_raw, 0, M_EDGES * sizeof(float), stream);

    k_dv   <<<dim3(N_NODES / 64),           dim3(256), 0, stream>>>(H, w, Dv_raw);
    k_lin  <<<dim3(N_NODES / 4),            dim3(256), 0, stream>>>(x, Wl, bl, Dv_raw, z);
    k_edge <<<dim3(M_EDGES / C3, 2),        dim3(T3),  0, stream>>>(H, z, t, De_raw);
    k_scale<<<dim3(M_EDGES * OUT_F / 256),  dim3(256), 0, stream>>>(t, w, De_raw);
    k_node <<<dim3(N_NODES / R5),           dim3(T5),  0, stream>>>(H, t, Dv_raw, out);
}